// Round 1
// baseline (277.449 us; speedup 1.0000x reference)
//
#include <hip/hip_runtime.h>
#include <stdint.h>

// Problem constants (from reference): B=128, K_fc=32 -> 4096 rows, F=2048,
// K_LIST = {64,128,256,512}, TAU=1, EPS=1e-20. Output = M_hard exactly
// (straight-through term is numerically zero in forward).

#define F_DIM   2048
#define NTHREADS 256
#define EPT     8          // elements per thread (2 x float4)
#define KSB     4

// Monotonic descending key: kd(a) < kd(b)  <=>  a > b  (total order on f32)
__device__ __forceinline__ uint32_t f32_desc_key(float x) {
    uint32_t u = __float_as_uint(x);
    uint32_t ka = (u & 0x80000000u) ? ~u : (u | 0x80000000u); // ascending
    return ~ka;                                               // descending
}

__global__ __launch_bounds__(NTHREADS)
void hsb_kernel(const float* __restrict__ scores,
                const float* __restrict__ uin,
                float* __restrict__ out) {
    const int row = blockIdx.x;
    const int t   = threadIdx.x;

    __shared__ uint32_t hist0[2048];          // level-0: 11-bit digit
    __shared__ uint32_t coarse[256];          // 8-bin sums of hist0
    __shared__ uint32_t hist4[KSB][256];      // levels 1..4: 8-bit digit per selector
    __shared__ unsigned long long selP[KSB];  // accumulated prefix per selector
    __shared__ uint32_t selR[KSB];            // remaining rank per selector

    const int base = row * F_DIM;
    const float4* s4 = (const float4*)(scores + base);
    const float4* u4 = (const float4*)(uin + base);

    // ---- load + perturb + build unique 43-bit keys: (kd << 11) | idx ----
    unsigned long long key[EPT];
    #pragma unroll
    for (int h = 0; h < 2; ++h) {
        float4 sv = s4[t + h * NTHREADS];
        float4 uv = u4[t + h * NTHREADS];
        float ss[4] = {sv.x, sv.y, sv.z, sv.w};
        float uu[4] = {uv.x, uv.y, uv.z, uv.w};
        #pragma unroll
        for (int j = 0; j < 4; ++j) {
            // gumbel = -log(-log(u + EPS) + EPS); perturbed = scores + gumbel (TAU=1)
            float inner = -logf(uu[j] + 1e-20f);
            float g     = -logf(inner + 1e-20f);
            float p     = ss[j] + g;
            uint32_t idx = (uint32_t)(h * 1024 + 4 * t + j);
            key[h * 4 + j] = (((unsigned long long)f32_desc_key(p)) << 11) |
                             (unsigned long long)idx;
        }
    }

    // ---- level 0: 11-bit digit (key bits 42:32) ----
    #pragma unroll
    for (int i = 0; i < 8; ++i) hist0[t + i * NTHREADS] = 0;
    __syncthreads();
    #pragma unroll
    for (int e = 0; e < EPT; ++e)
        atomicAdd(&hist0[(uint32_t)(key[e] >> 32)], 1u);
    __syncthreads();
    {
        uint32_t cs = 0;
        #pragma unroll
        for (int b = 0; b < 8; ++b) cs += hist0[8 * t + b];
        coarse[t] = cs;
    }
    __syncthreads();
    if (t < KSB) {
        const uint32_t Ks[KSB] = {64u, 128u, 256u, 512u};
        uint32_t r = Ks[t] - 1u;
        uint32_t acc = 0;
        int cb = 0;
        for (; cb < 256; ++cb) {
            uint32_t n = coarse[cb];
            if (acc + n > r) break;
            acc += n;
        }
        int d = 8 * cb;
        for (;; ++d) {
            uint32_t n = hist0[d];
            if (acc + n > r) break;
            acc += n;
        }
        selP[t] = (unsigned long long)d;
        selR[t] = r - acc;
    }
    __syncthreads();

    // ---- levels 1..4: 8-bit digits (bits 31:24, 23:16, 15:8, 7:0) ----
    #pragma unroll
    for (int l = 1; l <= 4; ++l) {
        const int shift = 32 - 8 * l;
        unsigned long long p0 = selP[0], p1 = selP[1], p2 = selP[2], p3 = selP[3];
        #pragma unroll
        for (int i = 0; i < 4; ++i) ((uint32_t*)hist4)[t + i * NTHREADS] = 0;
        __syncthreads();
        #pragma unroll
        for (int e = 0; e < EPT; ++e) {
            unsigned long long hi = key[e] >> (shift + 8);
            uint32_t dg = (uint32_t)(key[e] >> shift) & 0xFFu;
            if (hi == p0) atomicAdd(&hist4[0][dg], 1u);
            if (hi == p1) atomicAdd(&hist4[1][dg], 1u);
            if (hi == p2) atomicAdd(&hist4[2][dg], 1u);
            if (hi == p3) atomicAdd(&hist4[3][dg], 1u);
        }
        __syncthreads();
        if (t < KSB) {
            uint32_t r = selR[t];
            uint32_t acc = 0;
            int d = 0;
            for (;; ++d) {
                uint32_t n = hist4[t][d];
                if (acc + n > r) break;
                acc += n;
            }
            selP[t] = (selP[t] << 8) | (unsigned long long)(uint32_t)d;
            selR[t] = r - acc;
        }
        __syncthreads();
    }

    // ---- write masks: rank < K  <=>  key <= T_K (keys unique) ----
    const unsigned long long T0 = selP[0], T1 = selP[1], T2 = selP[2], T3 = selP[3];
    float* outrow = out + (size_t)row * (KSB * F_DIM);
    #pragma unroll
    for (int h = 0; h < 2; ++h) {
        float4 m0, m1, m2, m3;
        float* f0 = (float*)&m0; float* f1 = (float*)&m1;
        float* f2 = (float*)&m2; float* f3 = (float*)&m3;
        #pragma unroll
        for (int j = 0; j < 4; ++j) {
            unsigned long long k = key[h * 4 + j];
            f0[j] = (k <= T0) ? 1.0f : 0.0f;
            f1[j] = (k <= T1) ? 1.0f : 0.0f;
            f2[j] = (k <= T2) ? 1.0f : 0.0f;
            f3[j] = (k <= T3) ? 1.0f : 0.0f;
        }
        const int off = h * 1024 + 4 * t;
        *(float4*)(outrow + 0 * F_DIM + off) = m0;
        *(float4*)(outrow + 1 * F_DIM + off) = m1;
        *(float4*)(outrow + 2 * F_DIM + off) = m2;
        *(float4*)(outrow + 3 * F_DIM + off) = m3;
    }
}

extern "C" void kernel_launch(void* const* d_in, const int* in_sizes, int n_in,
                              void* d_out, int out_size, void* d_ws, size_t ws_size,
                              hipStream_t stream) {
    const float* scores = (const float*)d_in[0];
    const float* u      = (const float*)d_in[1];
    float* out          = (float*)d_out;
    const int rows = in_sizes[0] / F_DIM;  // 4096
    hsb_kernel<<<dim3(rows), dim3(NTHREADS), 0, stream>>>(scores, u, out);
}

// Round 2
// 190.220 us; speedup vs baseline: 1.4586x; 1.4586x over previous
//
#include <hip/hip_runtime.h>
#include <stdint.h>

// B=128, K_fc=32 -> 4096 rows, F=2048, K_LIST={64,128,256,512}, TAU=1, EPS=1e-20.
// Output = M_hard exactly (straight-through term is numerically zero forward).
//
// R2: level-0 11-bit histogram select, then parallel prefix-scan + parallel
// bin-find (no serial scans), then candidate-collection + all-pairs rank for
// the within-bin refinement (replaces 4 histogram levels + serial scans).

#define F_DIM    2048
#define NT       256
#define EPT      8
#define KSB      4
#define CAP      512   // max candidates per selector bin (est. worst ~250)

// Monotonic descending key: kd(a) < kd(b)  <=>  a > b (total order on f32)
__device__ __forceinline__ uint32_t f32_desc_key(float x) {
    uint32_t u = __float_as_uint(x);
    uint32_t ka = (u & 0x80000000u) ? ~u : (u | 0x80000000u);
    return ~ka;
}

__global__ __launch_bounds__(NT)
void hsb_kernel(const float* __restrict__ scores,
                const float* __restrict__ uin,
                float* __restrict__ out) {
    const int row  = blockIdx.x;
    const int t    = threadIdx.x;
    const int lane = t & 63;
    const int wave = t >> 6;

    __shared__ uint32_t hist0[2048];          // 11-bit digit histogram
    __shared__ uint32_t cand[KSB][CAP];       // low-32 key bits of bin members
    __shared__ uint32_t waveSum[4];
    __shared__ uint32_t selBin[KSB];
    __shared__ uint32_t selRem[KSB];
    __shared__ uint32_t selCnt[KSB];
    __shared__ uint32_t selThr[KSB];

    const int base = row * F_DIM;
    const float4* s4 = (const float4*)(scores + base);
    const float4* u4 = (const float4*)(uin + base);

    // ---- load + perturb + unique 43-bit keys: (f32_desc_key(p) << 11) | idx ----
    unsigned long long key[EPT];
    #pragma unroll
    for (int h = 0; h < 2; ++h) {
        float4 sv = s4[t + h * NT];
        float4 uv = u4[t + h * NT];
        float ss[4] = {sv.x, sv.y, sv.z, sv.w};
        float uu[4] = {uv.x, uv.y, uv.z, uv.w};
        #pragma unroll
        for (int j = 0; j < 4; ++j) {
            float inner = -logf(uu[j] + 1e-20f);      // keep byte-identical math
            float g     = -logf(inner + 1e-20f);
            float p     = ss[j] + g;
            uint32_t idx = (uint32_t)(h * 1024 + 4 * t + j);
            key[h * 4 + j] = (((unsigned long long)f32_desc_key(p)) << 11) |
                             (unsigned long long)idx;
        }
    }

    // ---- zero histogram (vectorized, conflict-light) ----
    {
        uint4 z = {0u, 0u, 0u, 0u};
        ((uint4*)hist0)[2 * t + 0] = z;
        ((uint4*)hist0)[2 * t + 1] = z;
    }
    __syncthreads();                                           // B1

    // ---- level-0 histogram over top-11-bit digit ----
    #pragma unroll
    for (int e = 0; e < EPT; ++e)
        atomicAdd(&hist0[(uint32_t)(key[e] >> 32)], 1u);
    __syncthreads();                                           // B2

    // ---- parallel prefix scan over 2048 bins (thread t owns bins 8t..8t+7) ----
    uint32_t c[8], p[8];
    {
        uint4 a = ((uint4*)hist0)[2 * t + 0];
        uint4 b = ((uint4*)hist0)[2 * t + 1];
        c[0]=a.x; c[1]=a.y; c[2]=a.z; c[3]=a.w;
        c[4]=b.x; c[5]=b.y; c[6]=b.z; c[7]=b.w;
    }
    uint32_t run = 0;
    #pragma unroll
    for (int i = 0; i < 8; ++i) { p[i] = run; run += c[i]; }
    uint32_t v = run;                       // wave inclusive scan of per-thread totals
    #pragma unroll
    for (int d = 1; d < 64; d <<= 1) {
        uint32_t n = __shfl_up(v, (unsigned)d, 64);
        if (lane >= d) v += n;
    }
    if (lane == 63) waveSum[wave] = v;
    __syncthreads();                                           // B3
    uint32_t woff = 0;
    #pragma unroll
    for (int w = 0; w < 4; ++w) woff += (w < wave) ? waveSum[w] : 0u;
    const uint32_t thrOff = woff + v - run; // exclusive prefix of this thread's bins

    // ---- parallel bin-find for all 4 ranks (register-resident prefixes) ----
    if (t < KSB) selCnt[t] = 0;
    {
        const uint32_t Ks[KSB] = {64u, 128u, 256u, 512u};
        #pragma unroll
        for (int s = 0; s < KSB; ++s) {
            uint32_t r = Ks[s] - 1u;
            #pragma unroll
            for (int i = 0; i < 8; ++i) {
                uint32_t lo = thrOff + p[i];
                if (r >= lo && r < lo + c[i]) {
                    selBin[s] = (uint32_t)(8 * t + i);
                    selRem[s] = r - lo;
                }
            }
        }
    }
    __syncthreads();                                           // B4

    // ---- collect bin members' low-32 key bits per selector ----
    {
        const uint32_t b0 = selBin[0], b1 = selBin[1], b2 = selBin[2], b3 = selBin[3];
        #pragma unroll
        for (int e = 0; e < EPT; ++e) {
            uint32_t d  = (uint32_t)(key[e] >> 32);
            uint32_t lo = (uint32_t)key[e];
            if (d == b0) { uint32_t pos = atomicAdd(&selCnt[0], 1u); if (pos < CAP) cand[0][pos] = lo; }
            if (d == b1) { uint32_t pos = atomicAdd(&selCnt[1], 1u); if (pos < CAP) cand[1][pos] = lo; }
            if (d == b2) { uint32_t pos = atomicAdd(&selCnt[2], 1u); if (pos < CAP) cand[2][pos] = lo; }
            if (d == b3) { uint32_t pos = atomicAdd(&selCnt[3], 1u); if (pos < CAP) cand[3][pos] = lo; }
        }
    }
    __syncthreads();                                           // B5

    // ---- all-pairs rank within candidate set: wave s handles selector s ----
    {
        const int s = wave;
        const uint32_t C = min(selCnt[s], (uint32_t)CAP);
        const uint32_t r = selRem[s];
        for (uint32_t i = lane; i < C; i += 64) {
            uint32_t ci = cand[s][i];
            uint32_t cnt = 0;
            uint32_t j = 0;
            for (; j + 4 <= C; j += 4) {    // wave-uniform reads -> LDS broadcast
                cnt += (cand[s][j]     < ci);
                cnt += (cand[s][j + 1] < ci);
                cnt += (cand[s][j + 2] < ci);
                cnt += (cand[s][j + 3] < ci);
            }
            for (; j < C; ++j) cnt += (cand[s][j] < ci);
            if (cnt == r) selThr[s] = ci;   // unique keys -> exactly one writer
        }
    }
    __syncthreads();                                           // B6

    // ---- write masks: rank < K  <=>  key <= T_K (keys unique) ----
    const unsigned long long T0 = (((unsigned long long)selBin[0]) << 32) | selThr[0];
    const unsigned long long T1 = (((unsigned long long)selBin[1]) << 32) | selThr[1];
    const unsigned long long T2 = (((unsigned long long)selBin[2]) << 32) | selThr[2];
    const unsigned long long T3 = (((unsigned long long)selBin[3]) << 32) | selThr[3];
    float* outrow = out + (size_t)row * (KSB * F_DIM);
    #pragma unroll
    for (int h = 0; h < 2; ++h) {
        float4 m0, m1, m2, m3;
        float* f0 = (float*)&m0; float* f1 = (float*)&m1;
        float* f2 = (float*)&m2; float* f3 = (float*)&m3;
        #pragma unroll
        for (int j = 0; j < 4; ++j) {
            unsigned long long k = key[h * 4 + j];
            f0[j] = (k <= T0) ? 1.0f : 0.0f;
            f1[j] = (k <= T1) ? 1.0f : 0.0f;
            f2[j] = (k <= T2) ? 1.0f : 0.0f;
            f3[j] = (k <= T3) ? 1.0f : 0.0f;
        }
        const int off = h * 1024 + 4 * t;
        *(float4*)(outrow + 0 * F_DIM + off) = m0;
        *(float4*)(outrow + 1 * F_DIM + off) = m1;
        *(float4*)(outrow + 2 * F_DIM + off) = m2;
        *(float4*)(outrow + 3 * F_DIM + off) = m3;
    }
}

extern "C" void kernel_launch(void* const* d_in, const int* in_sizes, int n_in,
                              void* d_out, int out_size, void* d_ws, size_t ws_size,
                              hipStream_t stream) {
    const float* scores = (const float*)d_in[0];
    const float* u      = (const float*)d_in[1];
    float* out          = (float*)d_out;
    const int rows = in_sizes[0] / F_DIM;  // 4096
    hsb_kernel<<<dim3(rows), dim3(NT), 0, stream>>>(scores, u, out);
}

// Round 4
// 188.983 us; speedup vs baseline: 1.4681x; 1.0065x over previous
//
#include <hip/hip_runtime.h>
#include <stdint.h>

// B=128, K_fc=32 -> 4096 rows, F=2048, K_LIST={64,128,256,512}, TAU=1, EPS=1e-20.
// Output = M_hard exactly (straight-through term is numerically zero forward).
//
// R4 (= R3 with compile fix): single-level 13-bit radix histogram (packed u16
// counts in u32[4096]), fully parallel prefix scan + gated bin-find, tiny
// candidate set (C~5-30) resolved by trivial all-pairs. cand[] aliases dead
// histogram LDS. Nontemporal stores via native clang vector type (HIP float4
// is a class type -> rejected by __builtin_nontemporal_store).

#define F_DIM 2048
#define NT    256
#define EPT   8
#define KSB   4
#define CAP   256

typedef float f32x4 __attribute__((ext_vector_type(4)));

// Monotonic descending key: kd(a) < kd(b)  <=>  a > b (total order on f32)
__device__ __forceinline__ uint32_t f32_desc_key(float x) {
    uint32_t u = __float_as_uint(x);
    uint32_t ka = (u & 0x80000000u) ? ~u : (u | 0x80000000u);
    return ~ka;
}

__global__ __launch_bounds__(NT)
void hsb_kernel(const float* __restrict__ scores,
                const float* __restrict__ uin,
                float* __restrict__ out) {
    const int row  = blockIdx.x;
    const int t    = threadIdx.x;
    const int lane = t & 63;
    const int wave = t >> 6;

    // 8192 u16 bins packed into 4096 u32 words (16 KB).
    __shared__ uint32_t hist[4096];
    uint32_t (*cand)[CAP] = (uint32_t (*)[CAP])hist;  // alias: hist dead after scan
    __shared__ uint32_t waveSum[4];
    __shared__ uint32_t selBin[KSB];   // 13-bit digit of threshold bin
    __shared__ uint32_t selRem[KSB];   // residual rank within bin
    __shared__ uint32_t selCnt[KSB];
    __shared__ uint32_t selThr[KSB];   // low-30 key bits of threshold element

    const int base = row * F_DIM;
    const float4* s4 = (const float4*)(scores + base);
    const float4* u4 = (const float4*)(uin + base);

    // issue global loads early (long latency), zero hist while in flight
    float4 sv0 = s4[t];       float4 uv0 = u4[t];
    float4 sv1 = s4[t + NT];  float4 uv1 = u4[t + NT];
    {
        uint4 z = {0u, 0u, 0u, 0u};
        #pragma unroll
        for (int i = 0; i < 4; ++i) ((uint4*)hist)[t + i * NT] = z;
    }

    // ---- keys: (f32_desc_key(scores + gumbel) << 11) | idx  (43-bit, unique) ----
    unsigned long long key[EPT];
    {
        float ss[EPT] = {sv0.x, sv0.y, sv0.z, sv0.w, sv1.x, sv1.y, sv1.z, sv1.w};
        float uu[EPT] = {uv0.x, uv0.y, uv0.z, uv0.w, uv1.x, uv1.y, uv1.z, uv1.w};
        #pragma unroll
        for (int e = 0; e < EPT; ++e) {
            float inner = -logf(uu[e] + 1e-20f);    // byte-identical to reference math
            float g     = -logf(inner + 1e-20f);
            float p     = ss[e] + g;
            uint32_t idx = (uint32_t)((e < 4) ? (4 * t + e) : (1024 + 4 * t + (e - 4)));
            key[e] = (((unsigned long long)f32_desc_key(p)) << 11) |
                     (unsigned long long)idx;
        }
    }
    __syncthreads();                                           // B1

    // ---- 13-bit histogram: digit = key >> 30; packed u16 counts ----
    #pragma unroll
    for (int e = 0; e < EPT; ++e) {
        uint32_t dg = (uint32_t)(key[e] >> 30);
        atomicAdd(&hist[dg >> 1], 1u << ((dg & 1u) << 4));
    }
    __syncthreads();                                           // B2

    // ---- parallel scan: thread t owns words 16t..16t+15 (bins 32t..32t+31) ----
    uint32_t w16[16];
    {
        uint4 a = ((uint4*)hist)[4 * t + 0];
        uint4 b = ((uint4*)hist)[4 * t + 1];
        uint4 c = ((uint4*)hist)[4 * t + 2];
        uint4 d = ((uint4*)hist)[4 * t + 3];
        w16[0]=a.x; w16[1]=a.y; w16[2]=a.z;  w16[3]=a.w;
        w16[4]=b.x; w16[5]=b.y; w16[6]=b.z;  w16[7]=b.w;
        w16[8]=c.x; w16[9]=c.y; w16[10]=c.z; w16[11]=c.w;
        w16[12]=d.x; w16[13]=d.y; w16[14]=d.z; w16[15]=d.w;
    }
    uint32_t run = 0;
    #pragma unroll
    for (int i = 0; i < 16; ++i) run += (w16[i] & 0xFFFFu) + (w16[i] >> 16);
    uint32_t v = run;                 // wave inclusive scan of per-thread totals
    #pragma unroll
    for (int d = 1; d < 64; d <<= 1) {
        uint32_t n = __shfl_up(v, (unsigned)d, 64);
        if (lane >= d) v += n;
    }
    if (lane == 63) waveSum[wave] = v;
    __syncthreads();                                           // B3
    uint32_t woff = 0;
    #pragma unroll
    for (int w = 0; w < 4; ++w) woff += (w < wave) ? waveSum[w] : 0u;
    const uint32_t thrOff = woff + v - run;  // exclusive prefix of this thread's bins

    // ---- gated bin-find: only the owning lane walks its 16 words ----
    if (t < KSB) selCnt[t] = 0;
    {
        const uint32_t Ks[KSB] = {64u, 128u, 256u, 512u};
        #pragma unroll
        for (int s = 0; s < KSB; ++s) {
            uint32_t r = Ks[s] - 1u;
            if (r >= thrOff && r < thrOff + run) {
                uint32_t acc = thrOff;
                #pragma unroll
                for (int i = 0; i < 16; ++i) {
                    uint32_t c0 = w16[i] & 0xFFFFu, c1 = w16[i] >> 16;
                    if (r >= acc && r < acc + c0) { selBin[s] = 32u*t + 2u*i;      selRem[s] = r - acc; }
                    acc += c0;
                    if (r >= acc && r < acc + c1) { selBin[s] = 32u*t + 2u*i + 1u; selRem[s] = r - acc; }
                    acc += c1;
                }
            }
        }
    }
    __syncthreads();                                           // B4

    // ---- collect low-30 key bits of threshold-bin members (C ~ 5-30) ----
    {
        const uint32_t b0 = selBin[0], b1 = selBin[1], b2 = selBin[2], b3 = selBin[3];
        #pragma unroll
        for (int e = 0; e < EPT; ++e) {
            uint32_t dg = (uint32_t)(key[e] >> 30);
            uint32_t lo = (uint32_t)key[e] & 0x3FFFFFFFu;
            if (dg == b0) { uint32_t p = atomicAdd(&selCnt[0], 1u); if (p < CAP) cand[0][p] = lo; }
            if (dg == b1) { uint32_t p = atomicAdd(&selCnt[1], 1u); if (p < CAP) cand[1][p] = lo; }
            if (dg == b2) { uint32_t p = atomicAdd(&selCnt[2], 1u); if (p < CAP) cand[2][p] = lo; }
            if (dg == b3) { uint32_t p = atomicAdd(&selCnt[3], 1u); if (p < CAP) cand[3][p] = lo; }
        }
    }
    __syncthreads();                                           // B5

    // ---- tiny all-pairs rank within bin: wave s handles selector s ----
    {
        const int s = wave;
        const uint32_t C = min(selCnt[s], (uint32_t)CAP);
        const uint32_t r = selRem[s];
        for (uint32_t i = lane; i < C; i += 64) {
            uint32_t ci = cand[s][i];
            uint32_t cnt = 0;
            for (uint32_t j = 0; j < C; ++j) cnt += (cand[s][j] < ci);
            if (cnt == r) selThr[s] = ci;   // unique keys -> exactly one writer
        }
    }
    __syncthreads();                                           // B6

    // ---- write masks: rank < K  <=>  key <= T_K (keys unique) ----
    const unsigned long long T0 = (((unsigned long long)selBin[0]) << 30) | selThr[0];
    const unsigned long long T1 = (((unsigned long long)selBin[1]) << 30) | selThr[1];
    const unsigned long long T2 = (((unsigned long long)selBin[2]) << 30) | selThr[2];
    const unsigned long long T3 = (((unsigned long long)selBin[3]) << 30) | selThr[3];
    float* outrow = out + (size_t)row * (KSB * F_DIM);
    #pragma unroll
    for (int h = 0; h < 2; ++h) {
        f32x4 m0, m1, m2, m3;
        #pragma unroll
        for (int j = 0; j < 4; ++j) {
            unsigned long long k = key[h * 4 + j];
            m0[j] = (k <= T0) ? 1.0f : 0.0f;
            m1[j] = (k <= T1) ? 1.0f : 0.0f;
            m2[j] = (k <= T2) ? 1.0f : 0.0f;
            m3[j] = (k <= T3) ? 1.0f : 0.0f;
        }
        const int off = h * 1024 + 4 * t;
        __builtin_nontemporal_store(m0, (f32x4*)(outrow + 0 * F_DIM + off));
        __builtin_nontemporal_store(m1, (f32x4*)(outrow + 1 * F_DIM + off));
        __builtin_nontemporal_store(m2, (f32x4*)(outrow + 2 * F_DIM + off));
        __builtin_nontemporal_store(m3, (f32x4*)(outrow + 3 * F_DIM + off));
    }
}

extern "C" void kernel_launch(void* const* d_in, const int* in_sizes, int n_in,
                              void* d_out, int out_size, void* d_ws, size_t ws_size,
                              hipStream_t stream) {
    const float* scores = (const float*)d_in[0];
    const float* u      = (const float*)d_in[1];
    float* out          = (float*)d_out;
    const int rows = in_sizes[0] / F_DIM;  // 4096
    hsb_kernel<<<dim3(rows), dim3(NT), 0, stream>>>(scores, u, out);
}